// Round 2
// baseline (990.457 us; speedup 1.0000x reference)
//
#include <hip/hip_runtime.h>
#include <stdint.h>

#define T_TOK 4096
#define DM 1024
#define DF 4096
#define NE 8

typedef __attribute__((ext_vector_type(8))) short bf16x8;
typedef __attribute__((ext_vector_type(4))) float f32x4;

__device__ __forceinline__ float b2f(unsigned short u) {
    union { unsigned int i; float f; } v; v.i = ((unsigned int)u) << 16; return v.f;
}
__device__ __forceinline__ unsigned short f2b(float f) {
    unsigned int i = __float_as_uint(f);
    unsigned int r = (i + 0x7FFFu + ((i >> 16) & 1u)) >> 16;
    return (unsigned short)r;
}
__device__ __forceinline__ void load_lds16(const void* g, void* l) {
    __builtin_amdgcn_global_load_lds((__attribute__((address_space(1))) void*)(g),
                                     (__attribute__((address_space(3))) void*)(l), 16, 0, 0);
}

// ---------------- dtype detector: fp32 mantissa half-words hit exp==0xFF ~1/512 ----------------
__global__ __launch_bounds__(256) void detect_kernel(const unsigned short* __restrict__ xu,
                                                     int* __restrict__ flag) {
    int found = 0;
    for (int i = threadIdx.x; i < 262144; i += 256) {
        unsigned short u = xu[i];
        if (((u >> 7) & 0xFF) == 0xFF) found = 1;
    }
    if (found) atomicOr(flag, 1);
}

// ---------------- x -> bf16 (cast or copy) ----------------
__global__ __launch_bounds__(256) void convx_kernel(const void* __restrict__ xin,
                                                    const int* __restrict__ flag,
                                                    unsigned short* __restrict__ xb) {
    const size_t i = ((size_t)blockIdx.x * 256 + threadIdx.x) * 8;
    if (*flag) {
        const float* xf = (const float*)xin + i;
        float4 a = *(const float4*)xf;
        float4 b = *(const float4*)(xf + 4);
        alignas(16) unsigned short t[8] = { f2b(a.x), f2b(a.y), f2b(a.z), f2b(a.w),
                                            f2b(b.x), f2b(b.y), f2b(b.z), f2b(b.w) };
        *(uint4*)(xb + i) = *(const uint4*)t;
    } else {
        *(uint4*)(xb + i) = *(const uint4*)((const unsigned short*)xin + i);
    }
}

// ---------------- small arrays -> fp32 ----------------
__global__ void convf_kernel(const void* __restrict__ src, const int* __restrict__ flag,
                             float* __restrict__ dst, int n) {
    int i = blockIdx.x * 256 + threadIdx.x;
    if (i < n) dst[i] = (*flag) ? ((const float*)src)[i] : b2f(((const unsigned short*)src)[i]);
}

// ---------------- 64x64 tiled transpose + cast to bf16, per expert ----------------
__global__ __launch_bounds__(256) void transpose_kernel(const void* __restrict__ in,
                                                        unsigned short* __restrict__ out,
                                                        int R, int C, const int* __restrict__ flag) {
    __shared__ unsigned short tile[64][65];
    const int isf = *flag;
    const size_t base = (size_t)blockIdx.z * R * C;
    const int r0 = blockIdx.y * 64, c0 = blockIdx.x * 64;
    const int lr = threadIdx.x >> 2;           // 0..63
    const int lc = (threadIdx.x & 3) * 16;     // 0,16,32,48
    if (isf) {
        const float* src = (const float*)in + base + (size_t)(r0 + lr) * C + c0 + lc;
#pragma unroll
        for (int q = 0; q < 4; q++) {
            float4 v = *(const float4*)(src + q * 4);
            tile[lr][lc + q * 4 + 0] = f2b(v.x);
            tile[lr][lc + q * 4 + 1] = f2b(v.y);
            tile[lr][lc + q * 4 + 2] = f2b(v.z);
            tile[lr][lc + q * 4 + 3] = f2b(v.w);
        }
    } else {
        const unsigned short* src = (const unsigned short*)in + base + (size_t)(r0 + lr) * C + c0 + lc;
#pragma unroll
        for (int q = 0; q < 2; q++) {
            uint4 v = *(const uint4*)(src + q * 8);
            unsigned int w[4] = { v.x, v.y, v.z, v.w };
#pragma unroll
            for (int j = 0; j < 4; j++) {
                tile[lr][lc + q * 8 + 2 * j]     = (unsigned short)(w[j] & 0xffff);
                tile[lr][lc + q * 8 + 2 * j + 1] = (unsigned short)(w[j] >> 16);
            }
        }
    }
    __syncthreads();
    const int oc = threadIdx.x >> 2;           // output row (input col)
    const int oj = (threadIdx.x & 3) * 16;     // output col chunk (input rows)
    alignas(16) unsigned short tmp[16];
#pragma unroll
    for (int j = 0; j < 16; j++) tmp[j] = tile[oj + j][oc];
    unsigned short* dst = out + base + (size_t)(c0 + oc) * R + r0 + oj;
    *(uint4*)(dst) = *(const uint4*)(tmp);
    *(uint4*)(dst + 8) = *(const uint4*)(tmp + 8);
}

// ---------------- gate: one wave per token, original-precision logits ----------------
__global__ __launch_bounds__(256) void gate_kernel(
    const void* __restrict__ x, const void* __restrict__ Wg, const void* __restrict__ bg,
    const int* __restrict__ flag, int* __restrict__ cnt,
    int* __restrict__ tok_e, float* __restrict__ tok_s) {
    const int isf = *flag;
    const int wave = threadIdx.x >> 6, lane = threadIdx.x & 63;
    const int t = blockIdx.x * 4 + wave;
    float p[8] = {0.f,0.f,0.f,0.f,0.f,0.f,0.f,0.f};
    if (isf) {
        const float* xr = (const float*)x + (size_t)t * DM;
        const float* wg = (const float*)Wg;
        for (int i = lane; i < DM; i += 64) {
            float xv = xr[i];
            float4 a = *(const float4*)(wg + (size_t)i * 8);
            float4 b = *(const float4*)(wg + (size_t)i * 8 + 4);
            p[0] += xv * a.x; p[1] += xv * a.y; p[2] += xv * a.z; p[3] += xv * a.w;
            p[4] += xv * b.x; p[5] += xv * b.y; p[6] += xv * b.z; p[7] += xv * b.w;
        }
    } else {
        const unsigned short* xr = (const unsigned short*)x + (size_t)t * DM;
        const unsigned short* wg = (const unsigned short*)Wg;
        for (int i = lane; i < DM; i += 64) {
            float xv = b2f(xr[i]);
            uint4 wv = *(const uint4*)(wg + (size_t)i * 8);
            p[0] += xv * b2f((unsigned short)(wv.x & 0xffff));
            p[1] += xv * b2f((unsigned short)(wv.x >> 16));
            p[2] += xv * b2f((unsigned short)(wv.y & 0xffff));
            p[3] += xv * b2f((unsigned short)(wv.y >> 16));
            p[4] += xv * b2f((unsigned short)(wv.z & 0xffff));
            p[5] += xv * b2f((unsigned short)(wv.z >> 16));
            p[6] += xv * b2f((unsigned short)(wv.w & 0xffff));
            p[7] += xv * b2f((unsigned short)(wv.w >> 16));
        }
    }
    for (int off = 32; off > 0; off >>= 1)
        for (int e = 0; e < 8; e++) p[e] += __shfl_down(p[e], off);
    if (lane == 0) {
        for (int e = 0; e < 8; e++)
            p[e] += isf ? ((const float*)bg)[e] : b2f(((const unsigned short*)bg)[e]);
        int e0 = 0;
        for (int e = 1; e < 8; e++) if (p[e] > p[e0]) e0 = e;
        int e1 = (e0 == 0) ? 1 : 0;
        for (int e = 0; e < 8; e++) if (e != e0 && p[e] > p[e1]) e1 = e;
        float z = expf(p[e1] - p[e0]);       // l1 <= l0
        float s0 = 1.f / (1.f + z);
        tok_e[2 * t] = e0; tok_e[2 * t + 1] = e1;
        tok_s[2 * t] = s0; tok_s[2 * t + 1] = z * s0;
        atomicAdd(&cnt[e0], 1); atomicAdd(&cnt[e1], 1);
    }
}

__global__ void scan_kernel(const int* __restrict__ cnt, int* __restrict__ offs) {
    if (threadIdx.x == 0) {
        int s = 0;
        for (int e = 0; e < NE; e++) { offs[e] = s; s += cnt[e]; }
    }
}

__global__ __launch_bounds__(256) void place_kernel(
    const int* __restrict__ tok_e, const int* __restrict__ offs, int* __restrict__ cnt2,
    int* __restrict__ tok_list, int* __restrict__ slot_of) {
    const int t = blockIdx.x * 256 + threadIdx.x;
    for (int k = 0; k < 2; k++) {
        int e = tok_e[2 * t + k];
        int slot = atomicAdd(&cnt2[e], 1);
        int idx = offs[e] + slot;
        tok_list[idx] = t;
        slot_of[2 * t + k] = idx;
    }
}

// ---------------- GEMM1: gathered tokens @ W1^T, +b1, activation -> act (bf16) ----------------
__global__ __launch_bounds__(256) void gemm1_kernel(
    const unsigned short* __restrict__ xb, const unsigned short* __restrict__ W1T,
    const float* __restrict__ b1f, const int* __restrict__ tok_list,
    const int* __restrict__ offs, const int* __restrict__ cnt,
    unsigned short* __restrict__ act) {
    const int e = blockIdx.z, by = blockIdx.y, bx = blockIdx.x;
    const int ne = cnt[e];
    if (by * 128 >= ne) return;
    const int off_e = offs[e];
    __shared__ unsigned short Asm[128 * 32];
    __shared__ unsigned short Bsm[128 * 32];
    __shared__ int toks[128];
    const int tid = threadIdx.x, w = tid >> 6, lane = tid & 63;
    if (tid < 128) {
        int r = by * 128 + tid;
        toks[tid] = tok_list[off_e + (r < ne ? r : ne - 1)];
    }
    __syncthreads();
    const int arow0 = w * 16 + (lane >> 2);
    const int acol = (lane & 3) * 8;
    const int tok0 = toks[arow0], tok1 = toks[arow0 + 64];
    const unsigned short* gA0 = xb + (size_t)tok0 * DM + acol;
    const unsigned short* gA1 = xb + (size_t)tok1 * DM + acol;
    const unsigned short* Wte = W1T + (size_t)e * DF * DM;
    const unsigned short* gB0 = Wte + (size_t)(bx * 128 + arow0) * DM + acol;
    const unsigned short* gB1 = gB0 + (size_t)64 * DM;
    unsigned short* ldsA0 = &Asm[(w) * 16 * 32];
    unsigned short* ldsA1 = &Asm[(w + 4) * 16 * 32];
    unsigned short* ldsB0 = &Bsm[(w) * 16 * 32];
    unsigned short* ldsB1 = &Bsm[(w + 4) * 16 * 32];
    f32x4 acc[4][4] = {};
    const int mb = (w >> 1) * 64, nb = (w & 1) * 64;
    for (int kk = 0; kk < DM; kk += 32) {
        load_lds16(gA0 + kk, ldsA0);
        load_lds16(gA1 + kk, ldsA1);
        load_lds16(gB0 + kk, ldsB0);
        load_lds16(gB1 + kk, ldsB1);
        __syncthreads();
        bf16x8 af[4], bfv[4];
#pragma unroll
        for (int i = 0; i < 4; i++)
            af[i] = *(const bf16x8*)&Asm[(mb + i * 16 + (lane & 15)) * 32 + (lane >> 4) * 8];
#pragma unroll
        for (int j = 0; j < 4; j++)
            bfv[j] = *(const bf16x8*)&Bsm[(nb + j * 16 + (lane & 15)) * 32 + (lane >> 4) * 8];
#pragma unroll
        for (int i = 0; i < 4; i++)
#pragma unroll
            for (int j = 0; j < 4; j++)
                acc[i][j] = __builtin_amdgcn_mfma_f32_16x16x32_bf16(af[i], bfv[j], acc[i][j], 0, 0, 0);
        __syncthreads();
    }
    const bool even_e = (e & 1) == 0;
    const float* b1e = b1f + (size_t)e * DF + bx * 128;
#pragma unroll
    for (int i = 0; i < 4; i++) {
#pragma unroll
        for (int r = 0; r < 4; r++) {
            int m = mb + i * 16 + ((lane >> 4) * 4) + r;
            int grow = by * 128 + m;
            if (grow < ne) {
                unsigned short* dst = act + (size_t)(off_e + grow) * DF + bx * 128;
#pragma unroll
                for (int j = 0; j < 4; j++) {
                    int n = nb + j * 16 + (lane & 15);
                    float h = acc[i][j][r] + b1e[n];
                    float a;
                    if (even_e) a = 0.5f * h * (1.f + erff(h * 0.70710678118654752f));
                    else        a = h / (1.f + expf(-h));
                    dst[n] = f2b(a);
                }
            }
        }
    }
}

// ---------------- GEMM2: act @ W2^T, +b2 -> y (fp32 rows) ----------------
__global__ __launch_bounds__(256) void gemm2_kernel(
    const unsigned short* __restrict__ act, const unsigned short* __restrict__ W2T,
    const float* __restrict__ b2f, const int* __restrict__ offs,
    const int* __restrict__ cnt, float* __restrict__ yall) {
    const int e = blockIdx.z, by = blockIdx.y, bx = blockIdx.x;
    const int ne = cnt[e];
    if (by * 128 >= ne) return;
    const int off_e = offs[e];
    __shared__ unsigned short Asm[128 * 32];
    __shared__ unsigned short Bsm[128 * 32];
    const int tid = threadIdx.x, w = tid >> 6, lane = tid & 63;
    const int arow0 = w * 16 + (lane >> 2);
    const int acol = (lane & 3) * 8;
    int r0 = by * 128 + arow0;       if (r0 > ne - 1) r0 = ne - 1;
    int r1 = by * 128 + arow0 + 64;  if (r1 > ne - 1) r1 = ne - 1;
    const unsigned short* gA0 = act + (size_t)(off_e + r0) * DF + acol;
    const unsigned short* gA1 = act + (size_t)(off_e + r1) * DF + acol;
    const unsigned short* Wte = W2T + (size_t)e * DM * DF;
    const unsigned short* gB0 = Wte + (size_t)(bx * 128 + arow0) * DF + acol;
    const unsigned short* gB1 = gB0 + (size_t)64 * DF;
    unsigned short* ldsA0 = &Asm[(w) * 16 * 32];
    unsigned short* ldsA1 = &Asm[(w + 4) * 16 * 32];
    unsigned short* ldsB0 = &Bsm[(w) * 16 * 32];
    unsigned short* ldsB1 = &Bsm[(w + 4) * 16 * 32];
    f32x4 acc[4][4] = {};
    const int mb = (w >> 1) * 64, nb = (w & 1) * 64;
    for (int kk = 0; kk < DF; kk += 32) {
        load_lds16(gA0 + kk, ldsA0);
        load_lds16(gA1 + kk, ldsA1);
        load_lds16(gB0 + kk, ldsB0);
        load_lds16(gB1 + kk, ldsB1);
        __syncthreads();
        bf16x8 af[4], bfv[4];
#pragma unroll
        for (int i = 0; i < 4; i++)
            af[i] = *(const bf16x8*)&Asm[(mb + i * 16 + (lane & 15)) * 32 + (lane >> 4) * 8];
#pragma unroll
        for (int j = 0; j < 4; j++)
            bfv[j] = *(const bf16x8*)&Bsm[(nb + j * 16 + (lane & 15)) * 32 + (lane >> 4) * 8];
#pragma unroll
        for (int i = 0; i < 4; i++)
#pragma unroll
            for (int j = 0; j < 4; j++)
                acc[i][j] = __builtin_amdgcn_mfma_f32_16x16x32_bf16(af[i], bfv[j], acc[i][j], 0, 0, 0);
        __syncthreads();
    }
    const float* b2e = b2f + (size_t)e * DM + bx * 128;
#pragma unroll
    for (int i = 0; i < 4; i++) {
#pragma unroll
        for (int r = 0; r < 4; r++) {
            int m = mb + i * 16 + ((lane >> 4) * 4) + r;
            int grow = by * 128 + m;
            if (grow < ne) {
                float* dst = yall + (size_t)(off_e + grow) * DM + bx * 128;
#pragma unroll
                for (int j = 0; j < 4; j++) {
                    int n = nb + j * 16 + (lane & 15);
                    dst[n] = acc[i][j][r] + b2e[n];
                }
            }
        }
    }
}

// ---------------- combine: out[t] = s0*y[slot0] + s1*y[slot1], dtype per flag ----------------
__global__ __launch_bounds__(256) void combine_kernel(
    const float* __restrict__ yall, const int* __restrict__ slot_of,
    const float* __restrict__ tok_s, void* __restrict__ out, const int* __restrict__ flag) {
    const int t = blockIdx.x;
    const int c = threadIdx.x * 4;
    const int s0i = slot_of[2 * t], s1i = slot_of[2 * t + 1];
    const float w0 = tok_s[2 * t], w1 = tok_s[2 * t + 1];
    float4 a = *(const float4*)&yall[(size_t)s0i * DM + c];
    float4 b = *(const float4*)&yall[(size_t)s1i * DM + c];
    float4 r;
    r.x = w0 * a.x + w1 * b.x;
    r.y = w0 * a.y + w1 * b.y;
    r.z = w0 * a.z + w1 * b.z;
    r.w = w0 * a.w + w1 * b.w;
    if (*flag) {
        *(float4*)((float*)out + (size_t)t * DM + c) = r;
    } else {
        ushort4 o;
        o.x = f2b(r.x); o.y = f2b(r.y); o.z = f2b(r.z); o.w = f2b(r.w);
        *(ushort4*)((unsigned short*)out + (size_t)t * DM + c) = o;
    }
}

extern "C" void kernel_launch(void* const* d_in, const int* in_sizes, int n_in,
                              void* d_out, int out_size, void* d_ws, size_t ws_size,
                              hipStream_t stream) {
    (void)in_sizes; (void)n_in; (void)out_size; (void)ws_size;
    const void* x  = d_in[0];
    const void* W1 = d_in[1];
    const void* b1 = d_in[2];
    const void* W2 = d_in[3];
    const void* b2 = d_in[4];
    const void* Wg = d_in[5];
    const void* bg = d_in[6];

    uint8_t* wsb = (uint8_t*)d_ws;
    int* ip = (int*)wsb;
    int* flag  = ip;          // [0]
    int* cnt   = ip + 8;      // [8]
    int* cnt2  = ip + 16;     // [8]
    int* offs  = ip + 24;     // [8]
    int* tok_e = ip + 32;     // [2T]
    float* tok_s  = (float*)(tok_e + 2 * T_TOK);
    int* tok_list = (int*)(tok_s + 2 * T_TOK);
    int* slot_of  = tok_list + 2 * T_TOK;
    size_t head = (size_t)((uint8_t*)(slot_of + 2 * T_TOK) - wsb);
    head = (head + 255) & ~(size_t)255;
    float* b1f = (float*)(wsb + head);
    float* b2f = b1f + (size_t)NE * DF;
    unsigned short* xb  = (unsigned short*)(b2f + (size_t)NE * DM);
    unsigned short* W1T = xb + (size_t)T_TOK * DM;
    unsigned short* W2T = W1T + (size_t)NE * DM * DF;
    unsigned short* actb = W2T + (size_t)NE * DM * DF;
    float* yall = (float*)W1T;   // overlay: W1T dead after gemm1, yall written by gemm2

    hipMemsetAsync(ip, 0, 128, stream);   // zero flag + cnt + cnt2
    detect_kernel<<<1, 256, 0, stream>>>((const unsigned short*)x, flag);
    convx_kernel<<<(T_TOK * DM) / 2048, 256, 0, stream>>>(x, flag, xb);
    convf_kernel<<<(NE * DF) / 256, 256, 0, stream>>>(b1, flag, b1f, NE * DF);
    convf_kernel<<<(NE * DM) / 256, 256, 0, stream>>>(b2, flag, b2f, NE * DM);
    transpose_kernel<<<dim3(DF / 64, DM / 64, NE), 256, 0, stream>>>(W1, W1T, DM, DF, flag);
    transpose_kernel<<<dim3(DM / 64, DF / 64, NE), 256, 0, stream>>>(W2, W2T, DF, DM, flag);
    gate_kernel<<<T_TOK / 4, 256, 0, stream>>>(x, Wg, bg, flag, cnt, tok_e, tok_s);
    scan_kernel<<<1, 64, 0, stream>>>(cnt, offs);
    place_kernel<<<T_TOK / 256, 256, 0, stream>>>(tok_e, offs, cnt2, tok_list, slot_of);
    gemm1_kernel<<<dim3(DF / 128, T_TOK / 128, NE), 256, 0, stream>>>(xb, W1T, b1f, tok_list, offs, cnt, actb);
    gemm2_kernel<<<dim3(DM / 128, T_TOK / 128, NE), 256, 0, stream>>>(actb, W2T, b2f, offs, cnt, yall);
    combine_kernel<<<T_TOK, 256, 0, stream>>>(yall, slot_of, tok_s, d_out, flag);
}

// Round 3
// 764.730 us; speedup vs baseline: 1.2952x; 1.2952x over previous
//
#include <hip/hip_runtime.h>
#include <stdint.h>

#define T_TOK 4096
#define DM 1024
#define DF 4096
#define NE 8

typedef __attribute__((ext_vector_type(8))) short bf16x8;
typedef __attribute__((ext_vector_type(4))) float f32x4;

__device__ __forceinline__ float b2f(unsigned short u) {
    union { unsigned int i; float f; } v; v.i = ((unsigned int)u) << 16; return v.f;
}
__device__ __forceinline__ unsigned short f2b(float f) {
    unsigned int i = __float_as_uint(f);
    unsigned int r = (i + 0x7FFFu + ((i >> 16) & 1u)) >> 16;
    return (unsigned short)r;
}
__device__ __forceinline__ void load_lds16(const void* g, void* l) {
    __builtin_amdgcn_global_load_lds((__attribute__((address_space(1))) void*)(g),
                                     (__attribute__((address_space(3))) void*)(l), 16, 0, 0);
}

// ---------------- dtype detector (parallel): fp32 mantissa half-words hit exp==0xFF ~1/512 ----------------
__global__ __launch_bounds__(256) void detect_kernel(const unsigned short* __restrict__ xu,
                                                     int* __restrict__ flag) {
    const int i = (blockIdx.x * 256 + threadIdx.x) * 4;   // 256 blocks * 256 thr * 4 = 256K halfwords
    uint2 v = *(const uint2*)&xu[i];
    unsigned int a = v.x, b = v.y;
    int found = 0;
    if (((a >> 7)  & 0xFF) == 0xFF) found = 1;
    if (((a >> 23) & 0xFF) == 0xFF) found = 1;
    if (((b >> 7)  & 0xFF) == 0xFF) found = 1;
    if (((b >> 23) & 0xFF) == 0xFF) found = 1;
    if (__ballot(found) != 0 && (threadIdx.x & 63) == 0) atomicOr(flag, 1);
}

// ---------------- x -> bf16 (cast or copy) ----------------
__global__ __launch_bounds__(256) void convx_kernel(const void* __restrict__ xin,
                                                    const int* __restrict__ flag,
                                                    unsigned short* __restrict__ xb) {
    const size_t i = ((size_t)blockIdx.x * 256 + threadIdx.x) * 8;
    if (*flag) {
        const float* xf = (const float*)xin + i;
        float4 a = *(const float4*)xf;
        float4 b = *(const float4*)(xf + 4);
        alignas(16) unsigned short t[8] = { f2b(a.x), f2b(a.y), f2b(a.z), f2b(a.w),
                                            f2b(b.x), f2b(b.y), f2b(b.z), f2b(b.w) };
        *(uint4*)(xb + i) = *(const uint4*)t;
    } else {
        *(uint4*)(xb + i) = *(const uint4*)((const unsigned short*)xin + i);
    }
}

// ---------------- small arrays -> fp32 ----------------
__global__ void convf_kernel(const void* __restrict__ src, const int* __restrict__ flag,
                             float* __restrict__ dst, int n) {
    int i = blockIdx.x * 256 + threadIdx.x;
    if (i < n) dst[i] = (*flag) ? ((const float*)src)[i] : b2f(((const unsigned short*)src)[i]);
}

// ---------------- 64x64 tiled transpose + cast to bf16, per expert ----------------
__global__ __launch_bounds__(256) void transpose_kernel(const void* __restrict__ in,
                                                        unsigned short* __restrict__ out,
                                                        int R, int C, const int* __restrict__ flag) {
    __shared__ unsigned short tile[64][65];
    const int isf = *flag;
    const size_t base = (size_t)blockIdx.z * R * C;
    const int r0 = blockIdx.y * 64, c0 = blockIdx.x * 64;
    const int lr = threadIdx.x >> 2;           // 0..63
    const int lc = (threadIdx.x & 3) * 16;     // 0,16,32,48
    if (isf) {
        const float* src = (const float*)in + base + (size_t)(r0 + lr) * C + c0 + lc;
#pragma unroll
        for (int q = 0; q < 4; q++) {
            float4 v = *(const float4*)(src + q * 4);
            tile[lr][lc + q * 4 + 0] = f2b(v.x);
            tile[lr][lc + q * 4 + 1] = f2b(v.y);
            tile[lr][lc + q * 4 + 2] = f2b(v.z);
            tile[lr][lc + q * 4 + 3] = f2b(v.w);
        }
    } else {
        const unsigned short* src = (const unsigned short*)in + base + (size_t)(r0 + lr) * C + c0 + lc;
#pragma unroll
        for (int q = 0; q < 2; q++) {
            uint4 v = *(const uint4*)(src + q * 8);
            unsigned int w[4] = { v.x, v.y, v.z, v.w };
#pragma unroll
            for (int j = 0; j < 4; j++) {
                tile[lr][lc + q * 8 + 2 * j]     = (unsigned short)(w[j] & 0xffff);
                tile[lr][lc + q * 8 + 2 * j + 1] = (unsigned short)(w[j] >> 16);
            }
        }
    }
    __syncthreads();
    const int oc = threadIdx.x >> 2;           // output row (input col)
    const int oj = (threadIdx.x & 3) * 16;     // output col chunk (input rows)
    alignas(16) unsigned short tmp[16];
#pragma unroll
    for (int j = 0; j < 16; j++) tmp[j] = tile[oj + j][oc];
    unsigned short* dst = out + base + (size_t)(c0 + oc) * R + r0 + oj;
    *(uint4*)(dst) = *(const uint4*)(tmp);
    *(uint4*)(dst + 8) = *(const uint4*)(tmp + 8);
}

// ---------------- gate: one wave per token, original-precision logits ----------------
__global__ __launch_bounds__(256) void gate_kernel(
    const void* __restrict__ x, const void* __restrict__ Wg, const void* __restrict__ bg,
    const int* __restrict__ flag, int* __restrict__ cnt,
    int* __restrict__ tok_e, float* __restrict__ tok_s) {
    const int isf = *flag;
    const int wave = threadIdx.x >> 6, lane = threadIdx.x & 63;
    const int t = blockIdx.x * 4 + wave;
    float p[8] = {0.f,0.f,0.f,0.f,0.f,0.f,0.f,0.f};
    if (isf) {
        const float* xr = (const float*)x + (size_t)t * DM;
        const float* wg = (const float*)Wg;
        for (int i = lane; i < DM; i += 64) {
            float xv = xr[i];
            float4 a = *(const float4*)(wg + (size_t)i * 8);
            float4 b = *(const float4*)(wg + (size_t)i * 8 + 4);
            p[0] += xv * a.x; p[1] += xv * a.y; p[2] += xv * a.z; p[3] += xv * a.w;
            p[4] += xv * b.x; p[5] += xv * b.y; p[6] += xv * b.z; p[7] += xv * b.w;
        }
    } else {
        const unsigned short* xr = (const unsigned short*)x + (size_t)t * DM;
        const unsigned short* wg = (const unsigned short*)Wg;
        for (int i = lane; i < DM; i += 64) {
            float xv = b2f(xr[i]);
            uint4 wv = *(const uint4*)(wg + (size_t)i * 8);
            p[0] += xv * b2f((unsigned short)(wv.x & 0xffff));
            p[1] += xv * b2f((unsigned short)(wv.x >> 16));
            p[2] += xv * b2f((unsigned short)(wv.y & 0xffff));
            p[3] += xv * b2f((unsigned short)(wv.y >> 16));
            p[4] += xv * b2f((unsigned short)(wv.z & 0xffff));
            p[5] += xv * b2f((unsigned short)(wv.z >> 16));
            p[6] += xv * b2f((unsigned short)(wv.w & 0xffff));
            p[7] += xv * b2f((unsigned short)(wv.w >> 16));
        }
    }
    for (int off = 32; off > 0; off >>= 1)
        for (int e = 0; e < 8; e++) p[e] += __shfl_down(p[e], off);
    if (lane == 0) {
        for (int e = 0; e < 8; e++)
            p[e] += isf ? ((const float*)bg)[e] : b2f(((const unsigned short*)bg)[e]);
        int e0 = 0;
        for (int e = 1; e < 8; e++) if (p[e] > p[e0]) e0 = e;
        int e1 = (e0 == 0) ? 1 : 0;
        for (int e = 0; e < 8; e++) if (e != e0 && p[e] > p[e1]) e1 = e;
        float z = expf(p[e1] - p[e0]);       // l1 <= l0
        float s0 = 1.f / (1.f + z);
        tok_e[2 * t] = e0; tok_e[2 * t + 1] = e1;
        tok_s[2 * t] = s0; tok_s[2 * t + 1] = z * s0;
        atomicAdd(&cnt[e0], 1); atomicAdd(&cnt[e1], 1);
    }
}

__global__ void scan_kernel(const int* __restrict__ cnt, int* __restrict__ offs) {
    if (threadIdx.x == 0) {
        int s = 0;
        for (int e = 0; e < NE; e++) { offs[e] = s; s += cnt[e]; }
    }
}

__global__ __launch_bounds__(256) void place_kernel(
    const int* __restrict__ tok_e, const int* __restrict__ offs, int* __restrict__ cnt2,
    int* __restrict__ tok_list, int* __restrict__ slot_of) {
    const int t = blockIdx.x * 256 + threadIdx.x;
    for (int k = 0; k < 2; k++) {
        int e = tok_e[2 * t + k];
        int slot = atomicAdd(&cnt2[e], 1);
        int idx = offs[e] + slot;
        tok_list[idx] = t;
        slot_of[2 * t + k] = idx;
    }
}

// ---------------- GEMM1: gathered tokens @ W1^T, +b1, activation -> act (bf16) ----------------
__global__ __launch_bounds__(256) void gemm1_kernel(
    const unsigned short* __restrict__ xb, const unsigned short* __restrict__ W1T,
    const float* __restrict__ b1f, const int* __restrict__ tok_list,
    const int* __restrict__ offs, const int* __restrict__ cnt,
    unsigned short* __restrict__ act) {
    const int e = blockIdx.z, by = blockIdx.y, bx = blockIdx.x;
    const int ne = cnt[e];
    if (by * 128 >= ne) return;
    const int off_e = offs[e];
    __shared__ unsigned short Asm[128 * 32];
    __shared__ unsigned short Bsm[128 * 32];
    __shared__ int toks[128];
    const int tid = threadIdx.x, w = tid >> 6, lane = tid & 63;
    if (tid < 128) {
        int r = by * 128 + tid;
        toks[tid] = tok_list[off_e + (r < ne ? r : ne - 1)];
    }
    __syncthreads();
    const int arow0 = w * 16 + (lane >> 2);
    const int acol = (lane & 3) * 8;
    const int tok0 = toks[arow0], tok1 = toks[arow0 + 64];
    const unsigned short* gA0 = xb + (size_t)tok0 * DM + acol;
    const unsigned short* gA1 = xb + (size_t)tok1 * DM + acol;
    const unsigned short* Wte = W1T + (size_t)e * DF * DM;
    const unsigned short* gB0 = Wte + (size_t)(bx * 128 + arow0) * DM + acol;
    const unsigned short* gB1 = gB0 + (size_t)64 * DM;
    unsigned short* ldsA0 = &Asm[(w) * 16 * 32];
    unsigned short* ldsA1 = &Asm[(w + 4) * 16 * 32];
    unsigned short* ldsB0 = &Bsm[(w) * 16 * 32];
    unsigned short* ldsB1 = &Bsm[(w + 4) * 16 * 32];
    f32x4 acc[4][4] = {};
    const int mb = (w >> 1) * 64, nb = (w & 1) * 64;
    for (int kk = 0; kk < DM; kk += 32) {
        load_lds16(gA0 + kk, ldsA0);
        load_lds16(gA1 + kk, ldsA1);
        load_lds16(gB0 + kk, ldsB0);
        load_lds16(gB1 + kk, ldsB1);
        __syncthreads();
        bf16x8 af[4], bfv[4];
#pragma unroll
        for (int i = 0; i < 4; i++)
            af[i] = *(const bf16x8*)&Asm[(mb + i * 16 + (lane & 15)) * 32 + (lane >> 4) * 8];
#pragma unroll
        for (int j = 0; j < 4; j++)
            bfv[j] = *(const bf16x8*)&Bsm[(nb + j * 16 + (lane & 15)) * 32 + (lane >> 4) * 8];
#pragma unroll
        for (int i = 0; i < 4; i++)
#pragma unroll
            for (int j = 0; j < 4; j++)
                acc[i][j] = __builtin_amdgcn_mfma_f32_16x16x32_bf16(af[i], bfv[j], acc[i][j], 0, 0, 0);
        __syncthreads();
    }
    const bool even_e = (e & 1) == 0;
    const float* b1e = b1f + (size_t)e * DF + bx * 128;
#pragma unroll
    for (int i = 0; i < 4; i++) {
#pragma unroll
        for (int r = 0; r < 4; r++) {
            int m = mb + i * 16 + ((lane >> 4) * 4) + r;
            int grow = by * 128 + m;
            if (grow < ne) {
                unsigned short* dst = act + (size_t)(off_e + grow) * DF + bx * 128;
#pragma unroll
                for (int j = 0; j < 4; j++) {
                    int n = nb + j * 16 + (lane & 15);
                    float h = acc[i][j][r] + b1e[n];
                    float a;
                    if (even_e) a = 0.5f * h * (1.f + erff(h * 0.70710678118654752f));
                    else        a = h / (1.f + expf(-h));
                    dst[n] = f2b(a);
                }
            }
        }
    }
}

// ---------------- GEMM2: act @ W2^T, +b2 -> y (fp32 rows) ----------------
__global__ __launch_bounds__(256) void gemm2_kernel(
    const unsigned short* __restrict__ act, const unsigned short* __restrict__ W2T,
    const float* __restrict__ b2f, const int* __restrict__ offs,
    const int* __restrict__ cnt, float* __restrict__ yall) {
    const int e = blockIdx.z, by = blockIdx.y, bx = blockIdx.x;
    const int ne = cnt[e];
    if (by * 128 >= ne) return;
    const int off_e = offs[e];
    __shared__ unsigned short Asm[128 * 32];
    __shared__ unsigned short Bsm[128 * 32];
    const int tid = threadIdx.x, w = tid >> 6, lane = tid & 63;
    const int arow0 = w * 16 + (lane >> 2);
    const int acol = (lane & 3) * 8;
    int r0 = by * 128 + arow0;       if (r0 > ne - 1) r0 = ne - 1;
    int r1 = by * 128 + arow0 + 64;  if (r1 > ne - 1) r1 = ne - 1;
    const unsigned short* gA0 = act + (size_t)(off_e + r0) * DF + acol;
    const unsigned short* gA1 = act + (size_t)(off_e + r1) * DF + acol;
    const unsigned short* Wte = W2T + (size_t)e * DM * DF;
    const unsigned short* gB0 = Wte + (size_t)(bx * 128 + arow0) * DF + acol;
    const unsigned short* gB1 = gB0 + (size_t)64 * DF;
    unsigned short* ldsA0 = &Asm[(w) * 16 * 32];
    unsigned short* ldsA1 = &Asm[(w + 4) * 16 * 32];
    unsigned short* ldsB0 = &Bsm[(w) * 16 * 32];
    unsigned short* ldsB1 = &Bsm[(w + 4) * 16 * 32];
    f32x4 acc[4][4] = {};
    const int mb = (w >> 1) * 64, nb = (w & 1) * 64;
    for (int kk = 0; kk < DF; kk += 32) {
        load_lds16(gA0 + kk, ldsA0);
        load_lds16(gA1 + kk, ldsA1);
        load_lds16(gB0 + kk, ldsB0);
        load_lds16(gB1 + kk, ldsB1);
        __syncthreads();
        bf16x8 af[4], bfv[4];
#pragma unroll
        for (int i = 0; i < 4; i++)
            af[i] = *(const bf16x8*)&Asm[(mb + i * 16 + (lane & 15)) * 32 + (lane >> 4) * 8];
#pragma unroll
        for (int j = 0; j < 4; j++)
            bfv[j] = *(const bf16x8*)&Bsm[(nb + j * 16 + (lane & 15)) * 32 + (lane >> 4) * 8];
#pragma unroll
        for (int i = 0; i < 4; i++)
#pragma unroll
            for (int j = 0; j < 4; j++)
                acc[i][j] = __builtin_amdgcn_mfma_f32_16x16x32_bf16(af[i], bfv[j], acc[i][j], 0, 0, 0);
        __syncthreads();
    }
    const float* b2e = b2f + (size_t)e * DM + bx * 128;
#pragma unroll
    for (int i = 0; i < 4; i++) {
#pragma unroll
        for (int r = 0; r < 4; r++) {
            int m = mb + i * 16 + ((lane >> 4) * 4) + r;
            int grow = by * 128 + m;
            if (grow < ne) {
                float* dst = yall + (size_t)(off_e + grow) * DM + bx * 128;
#pragma unroll
                for (int j = 0; j < 4; j++) {
                    int n = nb + j * 16 + (lane & 15);
                    dst[n] = acc[i][j][r] + b2e[n];
                }
            }
        }
    }
}

// ---------------- combine: out[t] = s0*y[slot0] + s1*y[slot1], dtype per flag ----------------
__global__ __launch_bounds__(256) void combine_kernel(
    const float* __restrict__ yall, const int* __restrict__ slot_of,
    const float* __restrict__ tok_s, void* __restrict__ out, const int* __restrict__ flag) {
    const int t = blockIdx.x;
    const int c = threadIdx.x * 4;
    const int s0i = slot_of[2 * t], s1i = slot_of[2 * t + 1];
    const float w0 = tok_s[2 * t], w1 = tok_s[2 * t + 1];
    float4 a = *(const float4*)&yall[(size_t)s0i * DM + c];
    float4 b = *(const float4*)&yall[(size_t)s1i * DM + c];
    float4 r;
    r.x = w0 * a.x + w1 * b.x;
    r.y = w0 * a.y + w1 * b.y;
    r.z = w0 * a.z + w1 * b.z;
    r.w = w0 * a.w + w1 * b.w;
    if (*flag) {
        *(float4*)((float*)out + (size_t)t * DM + c) = r;
    } else {
        ushort4 o;
        o.x = f2b(r.x); o.y = f2b(r.y); o.z = f2b(r.z); o.w = f2b(r.w);
        *(ushort4*)((unsigned short*)out + (size_t)t * DM + c) = o;
    }
}

extern "C" void kernel_launch(void* const* d_in, const int* in_sizes, int n_in,
                              void* d_out, int out_size, void* d_ws, size_t ws_size,
                              hipStream_t stream) {
    (void)in_sizes; (void)n_in; (void)out_size; (void)ws_size;
    const void* x  = d_in[0];
    const void* W1 = d_in[1];
    const void* b1 = d_in[2];
    const void* W2 = d_in[3];
    const void* b2 = d_in[4];
    const void* Wg = d_in[5];
    const void* bg = d_in[6];

    uint8_t* wsb = (uint8_t*)d_ws;
    int* ip = (int*)wsb;
    int* flag  = ip;          // [0]
    int* cnt   = ip + 8;      // [8]
    int* cnt2  = ip + 16;     // [8]
    int* offs  = ip + 24;     // [8]
    int* tok_e = ip + 32;     // [2T]
    float* tok_s  = (float*)(tok_e + 2 * T_TOK);
    int* tok_list = (int*)(tok_s + 2 * T_TOK);
    int* slot_of  = tok_list + 2 * T_TOK;
    size_t head = (size_t)((uint8_t*)(slot_of + 2 * T_TOK) - wsb);
    head = (head + 255) & ~(size_t)255;
    float* b1f = (float*)(wsb + head);
    float* b2f = b1f + (size_t)NE * DF;
    unsigned short* xb  = (unsigned short*)(b2f + (size_t)NE * DM);
    unsigned short* W1T = xb + (size_t)T_TOK * DM;
    unsigned short* W2T = W1T + (size_t)NE * DM * DF;
    unsigned short* actb = W2T + (size_t)NE * DM * DF;
    float* yall = (float*)W1T;   // overlay: W1T dead after gemm1, yall written by gemm2

    hipMemsetAsync(ip, 0, 128, stream);   // zero flag + cnt + cnt2
    detect_kernel<<<256, 256, 0, stream>>>((const unsigned short*)x, flag);
    convx_kernel<<<(T_TOK * DM) / 2048, 256, 0, stream>>>(x, flag, xb);
    convf_kernel<<<(NE * DF) / 256, 256, 0, stream>>>(b1, flag, b1f, NE * DF);
    convf_kernel<<<(NE * DM) / 256, 256, 0, stream>>>(b2, flag, b2f, NE * DM);
    transpose_kernel<<<dim3(DF / 64, DM / 64, NE), 256, 0, stream>>>(W1, W1T, DM, DF, flag);
    transpose_kernel<<<dim3(DM / 64, DF / 64, NE), 256, 0, stream>>>(W2, W2T, DF, DM, flag);
    gate_kernel<<<T_TOK / 4, 256, 0, stream>>>(x, Wg, bg, flag, cnt, tok_e, tok_s);
    scan_kernel<<<1, 64, 0, stream>>>(cnt, offs);
    place_kernel<<<T_TOK / 256, 256, 0, stream>>>(tok_e, offs, cnt2, tok_list, slot_of);
    gemm1_kernel<<<dim3(DF / 128, T_TOK / 128, NE), 256, 0, stream>>>(xb, W1T, b1f, tok_list, offs, cnt, actb);
    gemm2_kernel<<<dim3(DM / 128, T_TOK / 128, NE), 256, 0, stream>>>(actb, W2T, b2f, offs, cnt, yall);
    combine_kernel<<<T_TOK, 256, 0, stream>>>(yall, slot_of, tok_s, d_out, flag);
}